// Round 1
// baseline (483.957 us; speedup 1.0000x reference)
//
#include <hip/hip_runtime.h>

#define TTOK  2048
#define HID   2048
#define IMID  768
#define NEXP  16
#define NPAIR 4096
#define NSLOT 4224          // 4096 + 128 slack
#define BM    128
#define BK    64
#define MAXT  48            // max tiles: 15 + 4096/128 = 47
#define ABUF  (128 * 64)    // one A/B buffer, shorts

// weight-convert chunking: 2048 floats per block
#define GUP_CHUNKS 24576    // 16*1536*2048 / 2048
#define DN_CHUNKS  12288    // 16*2048*768  / 2048

typedef __attribute__((ext_vector_type(8))) short  short8;
typedef __attribute__((ext_vector_type(4))) float  floatx4;

__device__ __forceinline__ unsigned pk2(float a, float b) {
    union { float f; unsigned u; } x{a}, y{b};
    unsigned ra = (x.u + 0x7FFFu + ((x.u >> 16) & 1u)) >> 16;
    unsigned rb = (y.u + 0x7FFFu + ((y.u >> 16) & 1u)) & 0xFFFF0000u;
    return ra | rb;
}

__device__ __forceinline__ short f2bf(float f) {
    union { float f; unsigned u; } v; v.f = f;
    return (short)((v.u + 0x7FFFu + ((v.u >> 16) & 1u)) >> 16);
}

__device__ __forceinline__ short8 cvt8(float4 a, float4 b) {
    union { unsigned u[4]; short8 s; } r;
    r.u[0] = pk2(a.x, a.y); r.u[1] = pk2(a.z, a.w);
    r.u[2] = pk2(b.x, b.y); r.u[3] = pk2(b.z, b.w);
    return r.s;
}

__device__ __forceinline__ void async_cp16(const void* g, void* l) {
    __builtin_amdgcn_global_load_lds(
        (const __attribute__((address_space(1))) void*)g,
        (__attribute__((address_space(3))) void*)l, 16, 0, 0);
}

// ---------- fused routing (block 0) + hs->bf16 (blocks 1..2048)
// ---------- + gate_up fp32->bf16 (next 24576) + down fp32->bf16 (next 12288)
__global__ __launch_bounds__(256) void k_pre(
    const float* __restrict__ hs, const int* __restrict__ idx,
    const float* __restrict__ tkw, const float* __restrict__ gup,
    const float* __restrict__ down, int* __restrict__ ntiles,
    int4* __restrict__ tiles, int* __restrict__ tok,
    float* __restrict__ wgt, short* __restrict__ X,
    short* __restrict__ gupb, short* __restrict__ downb)
{
    const int tid = threadIdx.x;
    const int bx  = (int)blockIdx.x;
    if (bx == 0) {
        __shared__ int cnt[NEXP], cur[NEXP];
        if (tid < NEXP) cnt[tid] = 0;
        __syncthreads();
        for (int i = tid; i < NPAIR; i += 256) atomicAdd(&cnt[idx[i]], 1);
        __syncthreads();
        if (tid == 0) {
            int s = 0, nt = 0;
            for (int e = 0; e < NEXP; e++) {
                cur[e] = s;
                int n = cnt[e];
                for (int tt = 0; tt * BM < n; tt++) {
                    tiles[nt] = make_int4(e, s + tt * BM, min(BM, n - tt * BM), 0);
                    nt++;
                }
                s += n;
            }
            *ntiles = nt;
        }
        __syncthreads();
        for (int i = tid; i < NPAIR; i += 256) {
            int e = idx[i];
            int p = atomicAdd(&cur[e], 1);
            tok[p] = i >> 1;
            wgt[p] = tkw[i];
        }
        for (int i = NPAIR + tid; i < NSLOT; i += 256) { tok[i] = 0; wgt[i] = 0.0f; }
    } else if (bx <= TTOK) {
        const int row = bx - 1;
        const float* src = hs + (size_t)row * HID + tid * 8;
        float4 a = *(const float4*)src;
        float4 b = *(const float4*)(src + 4);
        *(short8*)(X + (size_t)row * HID + tid * 8) = cvt8(a, b);
    } else if (bx <= TTOK + GUP_CHUNKS) {
        const size_t c = (size_t)(bx - 1 - TTOK);
        const float* src = gup + c * 2048 + tid * 8;
        float4 a = *(const float4*)src;
        float4 b = *(const float4*)(src + 4);
        *(short8*)(gupb + c * 2048 + tid * 8) = cvt8(a, b);
    } else {
        const size_t c = (size_t)(bx - 1 - TTOK - GUP_CHUNKS);
        const float* src = down + c * 2048 + tid * 8;
        float4 a = *(const float4*)src;
        float4 b = *(const float4*)(src + 4);
        *(short8*)(downb + c * 2048 + tid * 8) = cvt8(a, b);
    }
}

// ---------- GEMM1: X[tok] @ gate_up_bf16^T -> silu(g)*u*w -> mid (bf16) ----------
// grid (12 ct over I, MAXT tiles), block 256
__global__ __launch_bounds__(256, 2) void k_gemm1(
    const short* __restrict__ gupb, const short* __restrict__ X,
    const int* __restrict__ ntiles, const int4* __restrict__ tiles,
    const int* __restrict__ tok, const float* __restrict__ wgt,
    short* __restrict__ mid)
{
    if ((int)blockIdx.y >= *ntiles) return;
    const int4 td = tiles[blockIdx.y];
    const int e = td.x, rowstart = td.y, nvalid = td.z;
    const int ct = blockIdx.x;

    __shared__ short sA[2 * ABUF];
    __shared__ short sB[2 * ABUF];
    __shared__ int   s_tok[BM];
    __shared__ float s_w[BM];

    const int tid = threadIdx.x;
    if (tid < BM) { s_tok[tid] = tok[rowstart + tid]; s_w[tid] = wgt[rowstart + tid]; }
    __syncthreads();

    const int wave = tid >> 6, lane = tid & 63;
    const int m16 = lane & 15, quad = lane >> 4;

    // async-copy source params (XOR swizzle of 8-bf16 groups, LDS kept linear)
    const int lrow = tid >> 3;                 // 0..31
    const int gsw  = (tid & 7) ^ (lrow & 7);
    const short* aga[4];
    const short* bga[4];
#pragma unroll
    for (int j = 0; j < 4; j++)
        aga[j] = X + (size_t)s_tok[lrow + j * 32] * HID + gsw * 8;
    const short* gb = gupb + (size_t)e * (2 * IMID) * HID + gsw * 8;
#pragma unroll
    for (int j = 0; j < 2; j++) {
        bga[j]     = gb + (size_t)(ct * 64 + lrow + j * 32) * HID;          // gate rows
        bga[j + 2] = gb + (size_t)(IMID + ct * 64 + lrow + j * 32) * HID;   // up rows
    }

    auto stage = [&](int k0, short* dA, short* dB) {
#pragma unroll
        for (int j = 0; j < 4; j++)
            async_cp16(aga[j] + k0, dA + j * 2048 + wave * 512);
#pragma unroll
        for (int j = 0; j < 4; j++)
            async_cp16(bga[j] + k0, dB + j * 2048 + wave * 512);
    };

    const int Wm = (wave >> 1) << 6;   // 0 / 64
    const int Wi = (wave & 1) << 5;    // 0 / 32
    floatx4 ag[4][2], au[4][2];
#pragma unroll
    for (int a = 0; a < 4; a++)
#pragma unroll
        for (int b = 0; b < 2; b++) { ag[a][b] = (floatx4)0.0f; au[a][b] = (floatx4)0.0f; }

    stage(0, sA, sB);
    __syncthreads();

    const int nsteps = HID / BK;  // 32
    for (int ks = 0; ks < nsteps; ks++) {
        const short* Acur = sA + (ks & 1) * ABUF;
        const short* Bcur = sB + (ks & 1) * ABUF;
        if (ks + 1 < nsteps)
            stage((ks + 1) * BK, sA + ((ks + 1) & 1) * ABUF, sB + ((ks + 1) & 1) * ABUF);

#pragma unroll
        for (int h = 0; h < 2; h++) {
            short8 af[4];
#pragma unroll
            for (int mf = 0; mf < 4; mf++) {
                int row = Wm + mf * 16 + m16;
                int gc = (h * 4 + quad) ^ (row & 7);
                af[mf] = *(const short8*)&Acur[row * 64 + gc * 8];
            }
#pragma unroll
            for (int nf = 0; nf < 2; nf++) {
                int brow = Wi + nf * 16 + m16;
                int gcb = (h * 4 + quad) ^ (brow & 7);
                const short8 bg = *(const short8*)&Bcur[brow * 64 + gcb * 8];
                const short8 bu = *(const short8*)&Bcur[(64 + brow) * 64 + gcb * 8];
#pragma unroll
                for (int mf = 0; mf < 4; mf++) {
                    ag[mf][nf] = __builtin_amdgcn_mfma_f32_16x16x32_bf16(af[mf], bg, ag[mf][nf], 0, 0, 0);
                    au[mf][nf] = __builtin_amdgcn_mfma_f32_16x16x32_bf16(af[mf], bu, au[mf][nf], 0, 0, 0);
                }
            }
        }
        __syncthreads();
    }

    // epilogue: SwiGLU * router weight -> mid (bf16)
#pragma unroll
    for (int mf = 0; mf < 4; mf++) {
#pragma unroll
        for (int r = 0; r < 4; r++) {
            int m = Wm + mf * 16 + quad * 4 + r;
            if (m < nvalid) {
                float w = s_w[m];
                size_t rowp = (size_t)(rowstart + m) * IMID + ct * 64;
#pragma unroll
                for (int nf = 0; nf < 2; nf++) {
                    float g = ag[mf][nf][r], u = au[mf][nf][r];
                    float val = g / (1.0f + __expf(-g)) * u * w;
                    mid[rowp + Wi + nf * 16 + m16] = f2bf(val);
                }
            }
        }
    }
}

// ---------- GEMM2: mid @ down_bf16^T -> atomicAdd into out ----------
// grid (16 ct over H, MAXT tiles), block 256
__global__ __launch_bounds__(256, 2) void k_gemm2(
    const short* __restrict__ downb, const short* __restrict__ mid,
    const int* __restrict__ ntiles, const int4* __restrict__ tiles,
    const int* __restrict__ tok, float* __restrict__ out)
{
    if ((int)blockIdx.y >= *ntiles) return;
    const int4 td = tiles[blockIdx.y];
    const int e = td.x, rowstart = td.y, nvalid = td.z;
    const int ct = blockIdx.x;

    __shared__ short sA[2 * ABUF];
    __shared__ short sB[2 * ABUF];
    __shared__ int   s_tok[BM];

    const int tid = threadIdx.x;
    if (tid < BM) s_tok[tid] = tok[rowstart + tid];
    __syncthreads();

    const int wave = tid >> 6, lane = tid & 63;
    const int m16 = lane & 15, quad = lane >> 4;

    const int lrow = tid >> 3;
    const int gsw  = (tid & 7) ^ (lrow & 7);
    const short* aga[4];
    const short* bga[4];
#pragma unroll
    for (int j = 0; j < 4; j++)
        aga[j] = mid + (size_t)(rowstart + lrow + j * 32) * IMID + gsw * 8;
    const short* db = downb + ((size_t)e * HID + ct * 128) * IMID + gsw * 8;
#pragma unroll
    for (int j = 0; j < 4; j++)
        bga[j] = db + (size_t)(lrow + j * 32) * IMID;

    auto stage = [&](int k0, short* dA, short* dB) {
#pragma unroll
        for (int j = 0; j < 4; j++)
            async_cp16(aga[j] + k0, dA + j * 2048 + wave * 512);
#pragma unroll
        for (int j = 0; j < 4; j++)
            async_cp16(bga[j] + k0, dB + j * 2048 + wave * 512);
    };

    const int Wm = (wave >> 1) << 6;
    const int Wn = (wave & 1) << 6;   // 0 / 64 over the 128 H-cols
    floatx4 acc[4][4];
#pragma unroll
    for (int a = 0; a < 4; a++)
#pragma unroll
        for (int b = 0; b < 4; b++) acc[a][b] = (floatx4)0.0f;

    stage(0, sA, sB);
    __syncthreads();

    const int nsteps = IMID / BK;  // 12
    for (int ks = 0; ks < nsteps; ks++) {
        const short* Acur = sA + (ks & 1) * ABUF;
        const short* Bcur = sB + (ks & 1) * ABUF;
        if (ks + 1 < nsteps)
            stage((ks + 1) * BK, sA + ((ks + 1) & 1) * ABUF, sB + ((ks + 1) & 1) * ABUF);

#pragma unroll
        for (int h = 0; h < 2; h++) {
            short8 af[4];
#pragma unroll
            for (int mf = 0; mf < 4; mf++) {
                int row = Wm + mf * 16 + m16;
                int gc = (h * 4 + quad) ^ (row & 7);
                af[mf] = *(const short8*)&Acur[row * 64 + gc * 8];
            }
#pragma unroll
            for (int nf = 0; nf < 4; nf++) {
                int brow = Wn + nf * 16 + m16;
                int gcb = (h * 4 + quad) ^ (brow & 7);
                const short8 bf_ = *(const short8*)&Bcur[brow * 64 + gcb * 8];
#pragma unroll
                for (int mf = 0; mf < 4; mf++)
                    acc[mf][nf] = __builtin_amdgcn_mfma_f32_16x16x32_bf16(af[mf], bf_, acc[mf][nf], 0, 0, 0);
            }
        }
        __syncthreads();
    }

#pragma unroll
    for (int mf = 0; mf < 4; mf++) {
#pragma unroll
        for (int r = 0; r < 4; r++) {
            int m = Wm + mf * 16 + quad * 4 + r;
            if (m < nvalid) {
                int t = s_tok[m];
                float* op = out + (size_t)t * HID + ct * 128;
#pragma unroll
                for (int nf = 0; nf < 4; nf++)
                    atomicAdd(op + Wn + nf * 16 + m16, acc[mf][nf][r]);
            }
        }
    }
}

// ---------- launch ----------
extern "C" void kernel_launch(void* const* d_in, const int* in_sizes, int n_in,
                              void* d_out, int out_size, void* d_ws, size_t ws_size,
                              hipStream_t stream) {
    const float* hs   = (const float*)d_in[0];
    const int*   idx  = (const int*)d_in[1];
    const float* tkw  = (const float*)d_in[2];
    const float* gup  = (const float*)d_in[3];
    const float* down = (const float*)d_in[4];
    float* out = (float*)d_out;

    char* ws = (char*)d_ws;
    int*   ntiles = (int*)ws;
    int4*  tiles  = (int4*)(ws + 16);
    int*   tok    = (int*)(ws + 1024);
    float* wgt    = (float*)(ws + 1024 + NSLOT * 4);
    short* mid    = (short*)(ws + 36864);
    short* X      = (short*)(ws + 36864 + (size_t)NSLOT * IMID * 2);
    short* gupb   = (short*)(ws + (16u << 20));                         // 16 MiB
    short* downb  = (short*)(ws + (16u << 20) + (size_t)NEXP * 2 * IMID * HID * 2);

    hipMemsetAsync(d_out, 0, (size_t)TTOK * HID * sizeof(float), stream);
    k_pre  <<<1 + TTOK + GUP_CHUNKS + DN_CHUNKS, 256, 0, stream>>>(
        hs, idx, tkw, gup, down, ntiles, tiles, tok, wgt, X, gupb, downb);
    k_gemm1<<<dim3(IMID / 64, MAXT), 256, 0, stream>>>(gupb, X, ntiles, tiles, tok, wgt, mid);
    k_gemm2<<<dim3(HID / 128, MAXT), 256, 0, stream>>>(downb, mid, ntiles, tiles, tok, out);
}

// Round 2
// 476.528 us; speedup vs baseline: 1.0156x; 1.0156x over previous
//
#include <hip/hip_runtime.h>

#define TTOK  2048
#define HID   2048
#define IMID  768
#define NEXP  16
#define NPAIR 4096
#define NSLOT 4224          // 4096 + 128 slack
#define BM    128
#define BK    64
#define MAXT  48            // max tiles: 15 + 4096/128 = 47
#define ABUF  (128 * 64)    // one A/B buffer, shorts

// flat conversion index space (32B units = 8 floats)
#define HS_U   524288u      // 2048*2048/8
#define GUP_U  6291456u     // 16*1536*2048/8
#define DN_U   3145728u     // 16*2048*768/8
#define NU_TOT (HS_U + GUP_U + DN_U)

typedef __attribute__((ext_vector_type(8))) short  short8;
typedef __attribute__((ext_vector_type(4))) float  floatx4;

__device__ __forceinline__ unsigned pk2(float a, float b) {
    union { float f; unsigned u; } x{a}, y{b};
    unsigned ra = (x.u + 0x7FFFu + ((x.u >> 16) & 1u)) >> 16;
    unsigned rb = (y.u + 0x7FFFu + ((y.u >> 16) & 1u)) & 0xFFFF0000u;
    return ra | rb;
}

__device__ __forceinline__ short f2bf(float f) {
    union { float f; unsigned u; } v; v.f = f;
    return (short)((v.u + 0x7FFFu + ((v.u >> 16) & 1u)) >> 16);
}

__device__ __forceinline__ short8 cvt8(float4 a, float4 b) {
    union { unsigned u[4]; short8 s; } r;
    r.u[0] = pk2(a.x, a.y); r.u[1] = pk2(a.z, a.w);
    r.u[2] = pk2(b.x, b.y); r.u[3] = pk2(b.z, b.w);
    return r.s;
}

__device__ __forceinline__ void async_cp16(const void* g, void* l) {
    __builtin_amdgcn_global_load_lds(
        (const __attribute__((address_space(1))) void*)g,
        (__attribute__((address_space(3))) void*)l, 16, 0, 0);
}

// ---------- routing (block 0) + grid-stride fp32->bf16 convert of hs/gup/down ----------
__global__ __launch_bounds__(256) void k_pre(
    const float* __restrict__ hs, const int* __restrict__ idx,
    const float* __restrict__ tkw, const float* __restrict__ gup,
    const float* __restrict__ down, int* __restrict__ ntiles,
    int4* __restrict__ tiles, int* __restrict__ tok,
    float* __restrict__ wgt, short* __restrict__ X,
    short* __restrict__ gupb, short* __restrict__ downb)
{
    const int tid = threadIdx.x;
    if (blockIdx.x == 0) {
        __shared__ int cnt[NEXP], cur[NEXP];
        if (tid < NEXP) cnt[tid] = 0;
        __syncthreads();
        for (int i = tid; i < NPAIR; i += 256) atomicAdd(&cnt[idx[i]], 1);
        __syncthreads();
        if (tid == 0) {
            int s = 0, nt = 0;
            for (int e = 0; e < NEXP; e++) {
                cur[e] = s;
                int n = cnt[e];
                for (int tt = 0; tt * BM < n; tt++) {
                    tiles[nt] = make_int4(e, s + tt * BM, min(BM, n - tt * BM), 0);
                    nt++;
                }
                s += n;
            }
            *ntiles = nt;
        }
        __syncthreads();
        for (int i = tid; i < NPAIR; i += 256) {
            int e = idx[i];
            int p = atomicAdd(&cur[e], 1);
            tok[p] = i >> 1;
            wgt[p] = tkw[i];
        }
        for (int i = NPAIR + tid; i < NSLOT; i += 256) { tok[i] = 0; wgt[i] = 0.0f; }
        return;
    }
    // grid-stride streaming convert: independent iterations -> latency hidden
    const unsigned nthr = (gridDim.x - 1) * 256u;
    unsigned u = (blockIdx.x - 1) * 256u + tid;
    for (; u < NU_TOT; u += nthr) {
        const float* src; short* dst; unsigned off;
        if (u < HS_U)              { src = hs;   dst = X;     off = u; }
        else if (u < HS_U + GUP_U) { src = gup;  dst = gupb;  off = u - HS_U; }
        else                       { src = down; dst = downb; off = u - HS_U - GUP_U; }
        float4 a = *((const float4*)src + (size_t)2 * off);
        float4 b = *((const float4*)src + (size_t)2 * off + 1);
        *((short8*)dst + off) = cvt8(a, b);
    }
}

// ---------- GEMM1: X[tok] @ gate_up_bf16^T -> silu(g)*u*w -> mid (bf16) ----------
// grid (12 ct over I, MAXT tiles), block 256
__global__ __launch_bounds__(256, 2) void k_gemm1(
    const short* __restrict__ gupb, const short* __restrict__ X,
    const int* __restrict__ ntiles, const int4* __restrict__ tiles,
    const int* __restrict__ tok, const float* __restrict__ wgt,
    short* __restrict__ mid)
{
    if ((int)blockIdx.y >= *ntiles) return;
    const int4 td = tiles[blockIdx.y];
    const int e = td.x, rowstart = td.y, nvalid = td.z;
    const int ct = blockIdx.x;

    __shared__ short sA[2 * ABUF];
    __shared__ short sB[2 * ABUF];
    __shared__ int   s_tok[BM];
    __shared__ float s_w[BM];

    const int tid = threadIdx.x;
    if (tid < BM) { s_tok[tid] = tok[rowstart + tid]; s_w[tid] = wgt[rowstart + tid]; }
    __syncthreads();

    const int wave = tid >> 6, lane = tid & 63;
    const int m16 = lane & 15, quad = lane >> 4;

    // async-copy source params (XOR swizzle of 8-bf16 groups, LDS kept linear)
    const int lrow = tid >> 3;                 // 0..31
    const int gsw  = (tid & 7) ^ (lrow & 7);
    const short* aga[4];
    const short* bga[4];
#pragma unroll
    for (int j = 0; j < 4; j++)
        aga[j] = X + (size_t)s_tok[lrow + j * 32] * HID + gsw * 8;
    const short* gb = gupb + (size_t)e * (2 * IMID) * HID + gsw * 8;
#pragma unroll
    for (int j = 0; j < 2; j++) {
        bga[j]     = gb + (size_t)(ct * 64 + lrow + j * 32) * HID;          // gate rows
        bga[j + 2] = gb + (size_t)(IMID + ct * 64 + lrow + j * 32) * HID;   // up rows
    }

    auto stage = [&](int k0, short* dA, short* dB) {
#pragma unroll
        for (int j = 0; j < 4; j++)
            async_cp16(aga[j] + k0, dA + j * 2048 + wave * 512);
#pragma unroll
        for (int j = 0; j < 4; j++)
            async_cp16(bga[j] + k0, dB + j * 2048 + wave * 512);
    };

    const int Wm = (wave >> 1) << 6;   // 0 / 64
    const int Wi = (wave & 1) << 5;    // 0 / 32
    floatx4 ag[4][2], au[4][2];
#pragma unroll
    for (int a = 0; a < 4; a++)
#pragma unroll
        for (int b = 0; b < 2; b++) { ag[a][b] = (floatx4)0.0f; au[a][b] = (floatx4)0.0f; }

    stage(0, sA, sB);

    const int nsteps = HID / BK;  // 32
    for (int ks = 0; ks < nsteps; ks++) {
        const short* Acur = sA + (ks & 1) * ABUF;
        const short* Bcur = sB + (ks & 1) * ABUF;
        // T4: issue next tile, then wait only for the CURRENT tile's 8 loads.
        if (ks + 1 < nsteps) {
            stage((ks + 1) * BK, sA + ((ks + 1) & 1) * ABUF, sB + ((ks + 1) & 1) * ABUF);
            asm volatile("s_waitcnt vmcnt(8)" ::: "memory");
        } else {
            asm volatile("s_waitcnt vmcnt(0)" ::: "memory");
        }
        __builtin_amdgcn_s_barrier();
        __builtin_amdgcn_sched_barrier(0);

#pragma unroll
        for (int h = 0; h < 2; h++) {
            short8 af[4];
#pragma unroll
            for (int mf = 0; mf < 4; mf++) {
                int row = Wm + mf * 16 + m16;
                int gc = (h * 4 + quad) ^ (row & 7);
                af[mf] = *(const short8*)&Acur[row * 64 + gc * 8];
            }
#pragma unroll
            for (int nf = 0; nf < 2; nf++) {
                int brow = Wi + nf * 16 + m16;
                int gcb = (h * 4 + quad) ^ (brow & 7);
                const short8 bg = *(const short8*)&Bcur[brow * 64 + gcb * 8];
                const short8 bu = *(const short8*)&Bcur[(64 + brow) * 64 + gcb * 8];
#pragma unroll
                for (int mf = 0; mf < 4; mf++) {
                    ag[mf][nf] = __builtin_amdgcn_mfma_f32_16x16x32_bf16(af[mf], bg, ag[mf][nf], 0, 0, 0);
                    au[mf][nf] = __builtin_amdgcn_mfma_f32_16x16x32_bf16(af[mf], bu, au[mf][nf], 0, 0, 0);
                }
            }
        }
        __builtin_amdgcn_sched_barrier(0);
        __builtin_amdgcn_s_barrier();
    }

    // epilogue: SwiGLU * router weight -> mid (bf16)
#pragma unroll
    for (int mf = 0; mf < 4; mf++) {
#pragma unroll
        for (int r = 0; r < 4; r++) {
            int m = Wm + mf * 16 + quad * 4 + r;
            if (m < nvalid) {
                float w = s_w[m];
                size_t rowp = (size_t)(rowstart + m) * IMID + ct * 64;
#pragma unroll
                for (int nf = 0; nf < 2; nf++) {
                    float g = ag[mf][nf][r], u = au[mf][nf][r];
                    float val = g / (1.0f + __expf(-g)) * u * w;
                    mid[rowp + Wi + nf * 16 + m16] = f2bf(val);
                }
            }
        }
    }
}

// ---------- GEMM2: mid @ down_bf16^T -> atomicAdd into out ----------
// grid (16 ct over H, MAXT tiles), block 256
__global__ __launch_bounds__(256, 2) void k_gemm2(
    const short* __restrict__ downb, const short* __restrict__ mid,
    const int* __restrict__ ntiles, const int4* __restrict__ tiles,
    const int* __restrict__ tok, float* __restrict__ out)
{
    if ((int)blockIdx.y >= *ntiles) return;
    const int4 td = tiles[blockIdx.y];
    const int e = td.x, rowstart = td.y, nvalid = td.z;
    const int ct = blockIdx.x;

    __shared__ short sA[2 * ABUF];
    __shared__ short sB[2 * ABUF];
    __shared__ int   s_tok[BM];

    const int tid = threadIdx.x;
    if (tid < BM) s_tok[tid] = tok[rowstart + tid];
    __syncthreads();

    const int wave = tid >> 6, lane = tid & 63;
    const int m16 = lane & 15, quad = lane >> 4;

    const int lrow = tid >> 3;
    const int gsw  = (tid & 7) ^ (lrow & 7);
    const short* aga[4];
    const short* bga[4];
#pragma unroll
    for (int j = 0; j < 4; j++)
        aga[j] = mid + (size_t)(rowstart + lrow + j * 32) * IMID + gsw * 8;
    const short* db = downb + ((size_t)e * HID + ct * 128) * IMID + gsw * 8;
#pragma unroll
    for (int j = 0; j < 4; j++)
        bga[j] = db + (size_t)(lrow + j * 32) * IMID;

    auto stage = [&](int k0, short* dA, short* dB) {
#pragma unroll
        for (int j = 0; j < 4; j++)
            async_cp16(aga[j] + k0, dA + j * 2048 + wave * 512);
#pragma unroll
        for (int j = 0; j < 4; j++)
            async_cp16(bga[j] + k0, dB + j * 2048 + wave * 512);
    };

    const int Wm = (wave >> 1) << 6;
    const int Wn = (wave & 1) << 6;   // 0 / 64 over the 128 H-cols
    floatx4 acc[4][4];
#pragma unroll
    for (int a = 0; a < 4; a++)
#pragma unroll
        for (int b = 0; b < 4; b++) acc[a][b] = (floatx4)0.0f;

    stage(0, sA, sB);

    const int nsteps = IMID / BK;  // 12
    for (int ks = 0; ks < nsteps; ks++) {
        const short* Acur = sA + (ks & 1) * ABUF;
        const short* Bcur = sB + (ks & 1) * ABUF;
        if (ks + 1 < nsteps) {
            stage((ks + 1) * BK, sA + ((ks + 1) & 1) * ABUF, sB + ((ks + 1) & 1) * ABUF);
            asm volatile("s_waitcnt vmcnt(8)" ::: "memory");
        } else {
            asm volatile("s_waitcnt vmcnt(0)" ::: "memory");
        }
        __builtin_amdgcn_s_barrier();
        __builtin_amdgcn_sched_barrier(0);

#pragma unroll
        for (int h = 0; h < 2; h++) {
            short8 af[4];
#pragma unroll
            for (int mf = 0; mf < 4; mf++) {
                int row = Wm + mf * 16 + m16;
                int gc = (h * 4 + quad) ^ (row & 7);
                af[mf] = *(const short8*)&Acur[row * 64 + gc * 8];
            }
#pragma unroll
            for (int nf = 0; nf < 4; nf++) {
                int brow = Wn + nf * 16 + m16;
                int gcb = (h * 4 + quad) ^ (brow & 7);
                const short8 bf_ = *(const short8*)&Bcur[brow * 64 + gcb * 8];
#pragma unroll
                for (int mf = 0; mf < 4; mf++)
                    acc[mf][nf] = __builtin_amdgcn_mfma_f32_16x16x32_bf16(af[mf], bf_, acc[mf][nf], 0, 0, 0);
            }
        }
        __builtin_amdgcn_sched_barrier(0);
        __builtin_amdgcn_s_barrier();
    }

#pragma unroll
    for (int mf = 0; mf < 4; mf++) {
#pragma unroll
        for (int r = 0; r < 4; r++) {
            int m = Wm + mf * 16 + quad * 4 + r;
            if (m < nvalid) {
                int t = s_tok[m];
                float* op = out + (size_t)t * HID + ct * 128;
#pragma unroll
                for (int nf = 0; nf < 4; nf++)
                    atomicAdd(op + Wn + nf * 16 + m16, acc[mf][nf][r]);
            }
        }
    }
}

// ---------- launch ----------
extern "C" void kernel_launch(void* const* d_in, const int* in_sizes, int n_in,
                              void* d_out, int out_size, void* d_ws, size_t ws_size,
                              hipStream_t stream) {
    const float* hs   = (const float*)d_in[0];
    const int*   idx  = (const int*)d_in[1];
    const float* tkw  = (const float*)d_in[2];
    const float* gup  = (const float*)d_in[3];
    const float* down = (const float*)d_in[4];
    float* out = (float*)d_out;

    char* ws = (char*)d_ws;
    int*   ntiles = (int*)ws;
    int4*  tiles  = (int4*)(ws + 16);
    int*   tok    = (int*)(ws + 1024);
    float* wgt    = (float*)(ws + 1024 + NSLOT * 4);
    short* mid    = (short*)(ws + 36864);
    short* X      = (short*)(ws + 36864 + (size_t)NSLOT * IMID * 2);
    short* gupb   = (short*)(ws + (16u << 20));                         // 16 MiB
    short* downb  = (short*)(ws + (16u << 20) + (size_t)NEXP * 2 * IMID * HID * 2);

    hipMemsetAsync(d_out, 0, (size_t)TTOK * HID * sizeof(float), stream);
    k_pre  <<<2049, 256, 0, stream>>>(
        hs, idx, tkw, gup, down, ntiles, tiles, tok, wgt, X, gupb, downb);
    k_gemm1<<<dim3(IMID / 64, MAXT), 256, 0, stream>>>(gupb, X, ntiles, tiles, tok, wgt, mid);
    k_gemm2<<<dim3(HID / 128, MAXT), 256, 0, stream>>>(downb, mid, ntiles, tiles, tok, out);
}